// Round 2
// baseline (5806.372 us; speedup 1.0000x reference)
//
#include <hip/hip_runtime.h>
#include <hip/hip_bf16.h>
#include <stdint.h>

#define N_NODES   100000
#define N_EDGES   3200000
#define IN_FEAT   128
#define OUT_FEAT  128
#define NUM_RELS  16
#define NUM_BASES 8
#define M_PAD     100096      // 782 * 128

using short8 = __attribute__((ext_vector_type(8))) short;
using v4f    = __attribute__((ext_vector_type(4))) float;

__device__ inline unsigned short f2bf_rne(float f) {
    __hip_bfloat16 h = __float2bfloat16(f);
    return *reinterpret_cast<unsigned short*>(&h);
}
__device__ inline float bf2f(unsigned short u) {
    union { uint32_t i; float f; } x;
    x.i = ((uint32_t)u) << 16;
    return x.f;
}

// ---------------------------------------------------------------------------
// Kernel 1: Bt[n][k] = sum_b w_comp[r][b] * weight[b][k][o], n = r*128+o (bf16)
// B-operand layout: row n holds K contiguously.
// ---------------------------------------------------------------------------
__global__ void build_w(const float* __restrict__ weight,
                        const float* __restrict__ w_comp,
                        unsigned short* __restrict__ Bt) {
    int id = blockIdx.x * 256 + threadIdx.x;   // 2048*128 = 262144 total
    int n = id >> 7;
    int k = id & 127;
    int r = n >> 7;
    int o = n & 127;
    float acc = 0.f;
#pragma unroll
    for (int b = 0; b < NUM_BASES; ++b)
        acc += w_comp[r * NUM_BASES + b] * weight[(b * IN_FEAT + k) * OUT_FEAT + o];
    Bt[id] = f2bf_rne(acc);
}

// ---------------------------------------------------------------------------
// Kernel 2: out[n][o] = bias[o]   (d_out is poisoned before every launch)
// ---------------------------------------------------------------------------
__global__ void init_out(float* __restrict__ out, const float* __restrict__ bias) {
    int id = blockIdx.x * 256 + threadIdx.x;   // 12.8M
    out[id] = bias[id & 127];
}

// ---------------------------------------------------------------------------
// Kernel 3: per relation-chunk GEMM.
// h2[m][rl*128 + o] = sum_k x[m][k] * Bt[(c*RC+rl)*128+o][k]
// A staged from fp32 x with bf16 convert in regs; row-guard for m >= N_NODES.
// BM=128, BN=64, K=128 fully in LDS. 4 waves, 2x2, each 64x32 (4x2 MFMA tiles).
// LDS stride 136 bf16: row-to-row bank offset 4 -> only 2-way aliasing (free).
// ---------------------------------------------------------------------------
#define LDA 136
__global__ __launch_bounds__(256, 2) void gemm_h(const float* __restrict__ x,
                                                 const unsigned short* __restrict__ Bt,
                                                 unsigned short* __restrict__ h2,
                                                 int c, int RC) {
    __shared__ unsigned short lA[128 * LDA];   // 34816 B
    __shared__ unsigned short lB[64 * LDA];    // 17408 B

    const int mb = blockIdx.x;   // 0..781
    const int nb = blockIdx.y;   // 0..1
    const int rl = blockIdx.z;   // 0..RC-1
    const int r  = c * RC + rl;
    const int tid = threadIdx.x;

    // Stage A: 128 rows x 128 fp32 -> bf16 LDS (guard rows >= N_NODES)
    {
        const float* gA = x + (size_t)mb * 128 * IN_FEAT;
        const int rowbase = mb * 128;
#pragma unroll
        for (int it = 0; it < 16; ++it) {
            int ch = tid + it * 256;          // 0..4095 float4 chunks
            int row = ch >> 5;                // 32 chunks per row
            int col = (ch & 31) << 2;
            float4 v = make_float4(0.f, 0.f, 0.f, 0.f);
            if (rowbase + row < N_NODES)
                v = reinterpret_cast<const float4*>(gA)[ch];
            ushort4 o;
            o.x = f2bf_rne(v.x); o.y = f2bf_rne(v.y);
            o.z = f2bf_rne(v.z); o.w = f2bf_rne(v.w);
            *reinterpret_cast<ushort4*>(&lA[row * LDA + col]) = o;
        }
    }
    // Stage B: 64 rows x 128 bf16 (rows r*128+nb*64 .. +64 of Bt), contiguous 16 KB
    {
        const unsigned short* gB = Bt + ((size_t)r * 128 + nb * 64) * IN_FEAT;
#pragma unroll
        for (int it = 0; it < 4; ++it) {
            int ch = tid + it * 256;          // 1024 short8 chunks
            int row = ch >> 4;
            int col = (ch & 15) << 3;
            short8 v = *reinterpret_cast<const short8*>(gB + ch * 8);
            *reinterpret_cast<short8*>(&lB[row * LDA + col]) = v;
        }
    }
    __syncthreads();

    const int wid  = tid >> 6;
    const int lane = tid & 63;
    const int wm = wid >> 1;        // 0..1
    const int wn = wid & 1;         // 0..1
    const int ml   = lane & 15;
    const int kgrp = lane >> 4;     // 0..3

    v4f acc[4][2];
#pragma unroll
    for (int i = 0; i < 4; ++i)
#pragma unroll
        for (int j = 0; j < 2; ++j)
            acc[i][j] = (v4f){0.f, 0.f, 0.f, 0.f};

#pragma unroll
    for (int kb = 0; kb < 4; ++kb) {
        const int k0 = kb * 32 + kgrp * 8;
        short8 af[4], bfr[2];
#pragma unroll
        for (int tm = 0; tm < 4; ++tm)
            af[tm] = *reinterpret_cast<const short8*>(&lA[(wm * 64 + tm * 16 + ml) * LDA + k0]);
#pragma unroll
        for (int tn = 0; tn < 2; ++tn)
            bfr[tn] = *reinterpret_cast<const short8*>(&lB[(wn * 32 + tn * 16 + ml) * LDA + k0]);
#pragma unroll
        for (int tm = 0; tm < 4; ++tm)
#pragma unroll
            for (int tn = 0; tn < 2; ++tn)
                acc[tm][tn] = __builtin_amdgcn_mfma_f32_16x16x32_bf16(af[tm], bfr[tn], acc[tm][tn], 0, 0, 0);
    }

    // Epilogue: C/D layout col=lane&15, row=(lane>>4)*4+reg  [verified m89/m91]
    const int ncols = RC * 128;
    const int row0 = mb * 128 + wm * 64;
    const int col0 = rl * 128 + nb * 64 + wn * 32;
#pragma unroll
    for (int tm = 0; tm < 4; ++tm) {
#pragma unroll
        for (int tn = 0; tn < 2; ++tn) {
#pragma unroll
            for (int rr = 0; rr < 4; ++rr) {
                int row = row0 + tm * 16 + kgrp * 4 + rr;
                int col = col0 + tn * 16 + ml;
                h2[(size_t)row * ncols + col] = f2bf_rne(acc[tm][tn][rr]);
            }
        }
    }
}

// ---------------------------------------------------------------------------
// Kernel 4: per-edge scatter for relations [c*RC, (c+1)*RC):
// out[dst] += h2[src][ (et-c*RC)*128 .. +128 ]
// 32 lanes per edge, 4 floats per lane, fp32 hw atomics.
// ---------------------------------------------------------------------------
__global__ void scatter(const int* __restrict__ src, const int* __restrict__ dst,
                        const int* __restrict__ et,
                        const unsigned short* __restrict__ h2,
                        float* __restrict__ out, int c, int RC) {
    int tid = blockIdx.x * 256 + threadIdx.x;
    int e = tid >> 5;
    if (e >= N_EDGES) return;
    int t = et[e];
    int rlc = t - c * RC;
    if (rlc < 0 || rlc >= RC) return;
    int j = tid & 31;
    int s = src[e], d = dst[e];
    const ushort4 v = *reinterpret_cast<const ushort4*>(
        h2 + (size_t)s * ((size_t)RC * 128) + (size_t)rlc * 128 + j * 4);
    float* orow = out + (size_t)d * OUT_FEAT + j * 4;
    unsafeAtomicAdd(orow + 0, bf2f(v.x));
    unsafeAtomicAdd(orow + 1, bf2f(v.y));
    unsafeAtomicAdd(orow + 2, bf2f(v.z));
    unsafeAtomicAdd(orow + 3, bf2f(v.w));
}

extern "C" void kernel_launch(void* const* d_in, const int* in_sizes, int n_in,
                              void* d_out, int out_size, void* d_ws, size_t ws_size,
                              hipStream_t stream) {
    const float* x      = (const float*)d_in[0];
    const float* weight = (const float*)d_in[1];
    const float* w_comp = (const float*)d_in[2];
    const float* h_bias = (const float*)d_in[3];
    const int*   src    = (const int*)d_in[4];
    const int*   dst    = (const int*)d_in[5];
    const int*   etypes = (const int*)d_in[6];
    float* out = (float*)d_out;

    unsigned short* Bt = (unsigned short*)d_ws;                 // 512 KB
    const size_t h2_off = 1u << 20;                             // 1 MB aligned
    const size_t per_rel = (size_t)M_PAD * 128 * 2;             // 25,624,576 B
    int RC = 16;
    while (RC > 1 && h2_off + per_rel * (size_t)RC > ws_size) RC >>= 1;
    unsigned short* h2 = (unsigned short*)((char*)d_ws + h2_off);

    build_w<<<1024, 256, 0, stream>>>(weight, w_comp, Bt);
    init_out<<<50000, 256, 0, stream>>>(out, h_bias);

    const int nch = NUM_RELS / RC;
    for (int c = 0; c < nch; ++c) {
        gemm_h<<<dim3(782, 2, RC), 256, 0, stream>>>(x, Bt, h2, c, RC);
        scatter<<<400000, 256, 0, stream>>>(src, dst, etypes, h2, out, c, RC);
    }
}

// Round 3
// 1580.674 us; speedup vs baseline: 3.6734x; 3.6734x over previous
//
#include <hip/hip_runtime.h>
#include <hip/hip_bf16.h>
#include <stdint.h>

#define N_NODES   100000
#define N_EDGES   3200000
#define IN_FEAT   128
#define OUT_FEAT  128
#define NUM_RELS  16
#define NUM_BASES 8
#define M_PAD     100096      // 782 * 128

using short8 = __attribute__((ext_vector_type(8))) short;
using v4f    = __attribute__((ext_vector_type(4))) float;

__device__ inline unsigned short f2bf_rne(float f) {
    __hip_bfloat16 h = __float2bfloat16(f);
    return *reinterpret_cast<unsigned short*>(&h);
}
__device__ inline float bf2f(unsigned short u) {
    union { uint32_t i; float f; } x;
    x.i = ((uint32_t)u) << 16;
    return x.f;
}

// ---------------------------------------------------------------------------
// Bt[n][k] = sum_b w_comp[r][b] * weight[b][k][o], n = r*128+o (bf16)
// ---------------------------------------------------------------------------
__global__ void build_w(const float* __restrict__ weight,
                        const float* __restrict__ w_comp,
                        unsigned short* __restrict__ Bt) {
    int id = blockIdx.x * 256 + threadIdx.x;   // 262144 total
    int n = id >> 7;
    int k = id & 127;
    int r = n >> 7;
    int o = n & 127;
    float acc = 0.f;
#pragma unroll
    for (int b = 0; b < NUM_BASES; ++b)
        acc += w_comp[r * NUM_BASES + b] * weight[(b * IN_FEAT + k) * OUT_FEAT + o];
    Bt[id] = f2bf_rne(acc);
}

// ---------------------------------------------------------------------------
// Counting sort by dst: zero -> hist -> scan -> place
// ---------------------------------------------------------------------------
__global__ void zero_counts(int* __restrict__ count) {
    int id = blockIdx.x * 256 + threadIdx.x;
    if (id < N_NODES) count[id] = 0;
}

__global__ void hist(const int* __restrict__ dst, int* __restrict__ count) {
    int e = blockIdx.x * 256 + threadIdx.x;
    if (e < N_EDGES) atomicAdd(&count[dst[e]], 1);
}

// one block of 1024 threads: exclusive scan of count[0..N_NODES) -> off, cursor
__global__ __launch_bounds__(1024) void scan_kernel(const int* __restrict__ count,
                                                    int* __restrict__ off,
                                                    int* __restrict__ cursor) {
    __shared__ int part[1024];
    const int tid = threadIdx.x;
    const int CHUNK = 98;               // 1024*98 = 100352 >= 100000
    const int i0 = tid * CHUNK;
    int local = 0;
    for (int k = 0; k < CHUNK; ++k) {
        int i = i0 + k;
        if (i < N_NODES) local += count[i];
    }
    part[tid] = local;
    __syncthreads();
    // Hillis-Steele inclusive scan over 1024 partials
    for (int s = 1; s < 1024; s <<= 1) {
        int v = (tid >= s) ? part[tid - s] : 0;
        __syncthreads();
        part[tid] += v;
        __syncthreads();
    }
    int run = (tid > 0) ? part[tid - 1] : 0;   // exclusive base
    for (int k = 0; k < CHUNK; ++k) {
        int i = i0 + k;
        if (i < N_NODES) {
            off[i] = run;
            cursor[i] = run;
            run += count[i];
        }
    }
    if (tid == 1023) off[N_NODES] = part[1023];
}

__global__ void place(const int* __restrict__ src, const int* __restrict__ dst,
                      const int* __restrict__ et,
                      int* __restrict__ cursor, int* __restrict__ perm) {
    int e = blockIdx.x * 256 + threadIdx.x;
    if (e >= N_EDGES) return;
    int d = dst[e];
    int pos = atomicAdd(&cursor[d], 1);
    perm[pos] = (src[e] << 4) | et[e];         // src<2^17, et<16 -> 21 bits
}

// ---------------------------------------------------------------------------
// Per relation-chunk GEMM: h2[m][rl*128+o] = sum_k x[m][k] * Bt[(c*RC+rl)*128+o][k]
// ---------------------------------------------------------------------------
#define LDA 136
__global__ __launch_bounds__(256, 2) void gemm_h(const float* __restrict__ x,
                                                 const unsigned short* __restrict__ Bt,
                                                 unsigned short* __restrict__ h2,
                                                 int c, int RC) {
    __shared__ unsigned short lA[128 * LDA];
    __shared__ unsigned short lB[64 * LDA];

    const int mb = blockIdx.x;   // 0..781
    const int nb = blockIdx.y;   // 0..1
    const int rl = blockIdx.z;   // 0..RC-1
    const int r  = c * RC + rl;
    const int tid = threadIdx.x;

    {   // Stage A: 128 rows x 128 fp32 -> bf16 LDS (guard rows >= N_NODES)
        const float* gA = x + (size_t)mb * 128 * IN_FEAT;
        const int rowbase = mb * 128;
#pragma unroll
        for (int it = 0; it < 16; ++it) {
            int ch = tid + it * 256;
            int row = ch >> 5;
            int col = (ch & 31) << 2;
            float4 v = make_float4(0.f, 0.f, 0.f, 0.f);
            if (rowbase + row < N_NODES)
                v = reinterpret_cast<const float4*>(gA)[ch];
            ushort4 o;
            o.x = f2bf_rne(v.x); o.y = f2bf_rne(v.y);
            o.z = f2bf_rne(v.z); o.w = f2bf_rne(v.w);
            *reinterpret_cast<ushort4*>(&lA[row * LDA + col]) = o;
        }
    }
    {   // Stage B: 64 rows x 128 bf16, contiguous 16 KB
        const unsigned short* gB = Bt + ((size_t)r * 128 + nb * 64) * IN_FEAT;
#pragma unroll
        for (int it = 0; it < 4; ++it) {
            int ch = tid + it * 256;
            int row = ch >> 4;
            int col = (ch & 15) << 3;
            short8 v = *reinterpret_cast<const short8*>(gB + ch * 8);
            *reinterpret_cast<short8*>(&lB[row * LDA + col]) = v;
        }
    }
    __syncthreads();

    const int wid  = tid >> 6;
    const int lane = tid & 63;
    const int wm = wid >> 1;
    const int wn = wid & 1;
    const int ml   = lane & 15;
    const int kgrp = lane >> 4;

    v4f acc[4][2];
#pragma unroll
    for (int i = 0; i < 4; ++i)
#pragma unroll
        for (int j = 0; j < 2; ++j)
            acc[i][j] = (v4f){0.f, 0.f, 0.f, 0.f};

#pragma unroll
    for (int kb = 0; kb < 4; ++kb) {
        const int k0 = kb * 32 + kgrp * 8;
        short8 af[4], bfr[2];
#pragma unroll
        for (int tm = 0; tm < 4; ++tm)
            af[tm] = *reinterpret_cast<const short8*>(&lA[(wm * 64 + tm * 16 + ml) * LDA + k0]);
#pragma unroll
        for (int tn = 0; tn < 2; ++tn)
            bfr[tn] = *reinterpret_cast<const short8*>(&lB[(wn * 32 + tn * 16 + ml) * LDA + k0]);
#pragma unroll
        for (int tm = 0; tm < 4; ++tm)
#pragma unroll
            for (int tn = 0; tn < 2; ++tn)
                acc[tm][tn] = __builtin_amdgcn_mfma_f32_16x16x32_bf16(af[tm], bfr[tn], acc[tm][tn], 0, 0, 0);
    }

    // C/D layout: col=lane&15, row=(lane>>4)*4+reg  [verified m89/m91]
    const int ncols = RC * 128;
    const int row0 = mb * 128 + wm * 64;
    const int col0 = rl * 128 + nb * 64 + wn * 32;
#pragma unroll
    for (int tm = 0; tm < 4; ++tm)
#pragma unroll
        for (int tn = 0; tn < 2; ++tn)
#pragma unroll
            for (int rr = 0; rr < 4; ++rr) {
                int row = row0 + tm * 16 + kgrp * 4 + rr;
                int col = col0 + tn * 16 + ml;
                h2[(size_t)row * ncols + col] = f2bf_rne(acc[tm][tn][rr]);
            }
}

// ---------------------------------------------------------------------------
// Gather: one wave per destination node; edges pre-sorted by dst.
// out[d] = (c==0 ? bias : out[d]) + sum_{e in seg(d), et in chunk} h2[src_e][rl_e]
// Lane j accumulates floats 2j, 2j+1 (256 B coalesced h2 row read per edge).
// ---------------------------------------------------------------------------
__global__ void gather(const int* __restrict__ off, const int* __restrict__ perm,
                       const unsigned short* __restrict__ h2,
                       const float* __restrict__ bias,
                       float* __restrict__ out, int c, int RC) {
    const int d = blockIdx.x * 4 + (threadIdx.x >> 6);   // node id, 0..99999
    const int lane = threadIdx.x & 63;
    const int e0 = off[d], e1 = off[d + 1];
    const size_t rowstride = (size_t)RC * 128;
    float2 acc = make_float2(0.f, 0.f);
    for (int e = e0; e < e1; ++e) {
        int p = perm[e];                       // wave-uniform broadcast load
        int rl = (p & 15) - c * RC;
        if ((unsigned)rl >= (unsigned)RC) continue;   // wave-uniform branch
        int s = p >> 4;
        ushort2 v = *reinterpret_cast<const ushort2*>(h2 + (size_t)s * rowstride + rl * 128 + lane * 2);
        acc.x += bf2f(v.x);
        acc.y += bf2f(v.y);
    }
    float* po = out + (size_t)d * OUT_FEAT + lane * 2;
    if (c == 0) {
        acc.x += bias[lane * 2];
        acc.y += bias[lane * 2 + 1];
    } else {
        float2 prev = *reinterpret_cast<const float2*>(po);
        acc.x += prev.x;
        acc.y += prev.y;
    }
    *reinterpret_cast<float2*>(po) = acc;
}

extern "C" void kernel_launch(void* const* d_in, const int* in_sizes, int n_in,
                              void* d_out, int out_size, void* d_ws, size_t ws_size,
                              hipStream_t stream) {
    const float* x      = (const float*)d_in[0];
    const float* weight = (const float*)d_in[1];
    const float* w_comp = (const float*)d_in[2];
    const float* h_bias = (const float*)d_in[3];
    const int*   src    = (const int*)d_in[4];
    const int*   dst    = (const int*)d_in[5];
    const int*   etypes = (const int*)d_in[6];
    float* out = (float*)d_out;

    char* w = (char*)d_ws;
    unsigned short* Bt     = (unsigned short*)(w);                 // 512 KB
    int*            off    = (int*)(w + 0x100000);                 // 400,004 B
    int*            cursor = (int*)(w + 0x180000);                 // 400,000 B
    int*            perm   = (int*)(w + 0x200000);                 // 12.8 MB
    const size_t h2_off = 0x1000000;                               // 16 MB
    const size_t per_rel = (size_t)M_PAD * 128 * 2;                // 25,624,576 B
    int RC = 16;
    while (RC > 1 && h2_off + per_rel * (size_t)RC > ws_size) RC >>= 1;
    unsigned short* h2 = (unsigned short*)(w + h2_off);

    // sort edges by dst (counting sort)
    zero_counts<<<391, 256, 0, stream>>>(cursor);   // cursor reused as count
    hist<<<12500, 256, 0, stream>>>(dst, cursor);
    scan_kernel<<<1, 1024, 0, stream>>>(cursor, off, cursor);  // reads count, writes off+cursor
    place<<<12500, 256, 0, stream>>>(src, dst, etypes, cursor, perm);

    build_w<<<1024, 256, 0, stream>>>(weight, w_comp, Bt);

    const int nch = NUM_RELS / RC;
    for (int c = 0; c < nch; ++c) {
        gemm_h<<<dim3(782, 2, RC), 256, 0, stream>>>(x, Bt, h2, c, RC);
        gather<<<25000, 256, 0, stream>>>(off, perm, h2, h_bias, out, c, RC);
    }
}

// Round 4
// 850.997 us; speedup vs baseline: 6.8230x; 1.8574x over previous
//
#include <hip/hip_runtime.h>
#include <hip/hip_bf16.h>
#include <stdint.h>

#define N_NODES   100000
#define N_EDGES   3200000
#define IN_FEAT   128
#define OUT_FEAT  128
#define NUM_RELS  16
#define NUM_BASES 8
#define M_PAD     100096      // 782 * 128

using short8 = __attribute__((ext_vector_type(8))) short;
using v4f    = __attribute__((ext_vector_type(4))) float;

__device__ inline unsigned short f2bf_rne(float f) {
    __hip_bfloat16 h = __float2bfloat16(f);
    return *reinterpret_cast<unsigned short*>(&h);
}
__device__ inline float bf2f(unsigned short u) {
    union { uint32_t i; float f; } x;
    x.i = ((uint32_t)u) << 16;
    return x.f;
}

// ---------------------------------------------------------------------------
// x fp32 -> bf16, zero-padded to M_PAD rows
// ---------------------------------------------------------------------------
__global__ void conv_x(const float* __restrict__ x, unsigned short* __restrict__ xb) {
    int id = blockIdx.x * 256 + threadIdx.x;   // 3,203,072 threads, 4 elems each
    int base = id * 4;
    ushort4 o;
    if (base < N_NODES * IN_FEAT) {
        const float4 v = reinterpret_cast<const float4*>(x)[id];
        o.x = f2bf_rne(v.x); o.y = f2bf_rne(v.y);
        o.z = f2bf_rne(v.z); o.w = f2bf_rne(v.w);
    } else {
        o.x = o.y = o.z = o.w = 0;
    }
    reinterpret_cast<ushort4*>(xb)[id] = o;
}

// ---------------------------------------------------------------------------
// Bt[n][k] = sum_b w_comp[r][b] * weight[b][k][o], n = r*128+o (bf16)
// ---------------------------------------------------------------------------
__global__ void build_w(const float* __restrict__ weight,
                        const float* __restrict__ w_comp,
                        unsigned short* __restrict__ Bt) {
    int id = blockIdx.x * 256 + threadIdx.x;   // 262144
    int n = id >> 7;
    int k = id & 127;
    int r = n >> 7;
    int o = n & 127;
    float acc = 0.f;
#pragma unroll
    for (int b = 0; b < NUM_BASES; ++b)
        acc += w_comp[r * NUM_BASES + b] * weight[(b * IN_FEAT + k) * OUT_FEAT + o];
    Bt[id] = f2bf_rne(acc);
}

// ---------------------------------------------------------------------------
// Counting sort by key = (etype>>lg)*N_NODES + dst  (chunk-major, then dst)
// ---------------------------------------------------------------------------
__global__ void zero_counts(int* __restrict__ count, int K) {
    int id = blockIdx.x * 256 + threadIdx.x;
    if (id < K) count[id] = 0;
}

__global__ void hist(const int* __restrict__ dst, const int* __restrict__ et,
                     int* __restrict__ count, int lg) {
    int e = blockIdx.x * 256 + threadIdx.x;
    if (e < N_EDGES) atomicAdd(&count[(et[e] >> lg) * N_NODES + dst[e]], 1);
}

// 2-level exclusive scan of count[0..K) -> off, cursor. 4096 items/block.
__global__ void scan_part(const int* __restrict__ count, int* __restrict__ partial, int K) {
    __shared__ int sh[256];
    const int tid = threadIdx.x, b = blockIdx.x;
    const int i0 = b * 4096 + tid * 16;
    int s = 0;
#pragma unroll
    for (int k = 0; k < 16; ++k) { int i = i0 + k; if (i < K) s += count[i]; }
    sh[tid] = s;
    __syncthreads();
    for (int st = 128; st > 0; st >>= 1) {
        if (tid < st) sh[tid] += sh[tid + st];
        __syncthreads();
    }
    if (tid == 0) partial[b] = sh[0];
}

__global__ __launch_bounds__(512) void scan_mid(int* __restrict__ partial, int G,
                                                int* __restrict__ off, int K) {
    __shared__ int sh[512];
    const int tid = threadIdx.x;
    int v = (tid < G) ? partial[tid] : 0;
    sh[tid] = v;
    __syncthreads();
    for (int st = 1; st < 512; st <<= 1) {
        int t = (tid >= st) ? sh[tid - st] : 0;
        __syncthreads();
        sh[tid] += t;
        __syncthreads();
    }
    if (tid < G) partial[tid] = sh[tid] - v;        // exclusive
    if (tid == 511) off[K] = sh[511];               // total = N_EDGES
}

// NOTE: cursor may alias count — each element is read (sum + cnt) before
// being overwritten by the same thread, and no cross-block element access.
__global__ void scan_final(const int* __restrict__ count, const int* __restrict__ partial,
                           int* __restrict__ off, int* __restrict__ cursor, int K) {
    __shared__ int sh[256];
    const int tid = threadIdx.x, b = blockIdx.x;
    const int i0 = b * 4096 + tid * 16;
    int s = 0;
#pragma unroll
    for (int k = 0; k < 16; ++k) { int i = i0 + k; if (i < K) s += count[i]; }
    sh[tid] = s;
    __syncthreads();
    for (int st = 1; st < 256; st <<= 1) {
        int t = (tid >= st) ? sh[tid - st] : 0;
        __syncthreads();
        sh[tid] += t;
        __syncthreads();
    }
    int run = partial[b] + sh[tid] - s;   // exclusive prefix for this thread
#pragma unroll
    for (int k = 0; k < 16; ++k) {
        int i = i0 + k;
        if (i < K) {
            int cnt = count[i];
            off[i] = run;
            cursor[i] = run;
            run += cnt;
        }
    }
}

__global__ void place(const int* __restrict__ src, const int* __restrict__ dst,
                      const int* __restrict__ et,
                      int* __restrict__ cursor, int* __restrict__ perm,
                      int lg, int RCm1) {
    int e = blockIdx.x * 256 + threadIdx.x;
    if (e >= N_EDGES) return;
    int t = et[e];
    int key = (t >> lg) * N_NODES + dst[e];
    int pos = atomicAdd(&cursor[key], 1);
    perm[pos] = (src[e] << 4) | (t & RCm1);    // src<2^17, rl<16
}

// ---------------------------------------------------------------------------
// GEMM, m97-style: 128x128 tile, K=128 staged once via global_load_lds(16B)
// into XOR-swizzled LDS: 16B chunk (row,c) lives at slot row*16 + (c^(row&15)).
// Fragment ds_read_b128 then spreads banks (2-way per 16-lane phase = free).
// 4 waves in 2x2, each 64x64 = 4x4 MFMA 16x16x32 tiles.
// ---------------------------------------------------------------------------
__global__ __launch_bounds__(256, 2) void gemm_h(const unsigned short* __restrict__ xb,
                                                 const unsigned short* __restrict__ Bt,
                                                 unsigned short* __restrict__ h2,
                                                 int c, int RC) {
    __shared__ unsigned short lA[128 * 128];   // 32 KB
    __shared__ unsigned short lB[128 * 128];   // 32 KB

    const int mb = blockIdx.x;       // 0..781
    const int rl = blockIdx.y;       // 0..RC-1
    const int r  = c * RC + rl;
    const int tid  = threadIdx.x;
    const int wid  = tid >> 6;
    const int lane = tid & 63;

    const unsigned short* gA = xb + (size_t)mb * 128 * IN_FEAT;
    const unsigned short* gB = Bt + (size_t)r  * 128 * IN_FEAT;

#pragma unroll
    for (int it = 0; it < 8; ++it) {
        int sbase = it * 256 + wid * 64;
        int s = sbase + lane;
        int row = s >> 4;
        int cc = (s & 15) ^ (row & 15);
        __builtin_amdgcn_global_load_lds(
            (const __attribute__((address_space(1))) void*)(gA + row * 128 + cc * 8),
            (__attribute__((address_space(3))) void*)(&lA[sbase * 8]), 16, 0, 0);
    }
#pragma unroll
    for (int it = 0; it < 8; ++it) {
        int sbase = it * 256 + wid * 64;
        int s = sbase + lane;
        int row = s >> 4;
        int cc = (s & 15) ^ (row & 15);
        __builtin_amdgcn_global_load_lds(
            (const __attribute__((address_space(1))) void*)(gB + row * 128 + cc * 8),
            (__attribute__((address_space(3))) void*)(&lB[sbase * 8]), 16, 0, 0);
    }
    __syncthreads();

    const int wm = wid >> 1, wn = wid & 1;
    const int ml = lane & 15, kgrp = lane >> 4;

    v4f acc[4][4];
#pragma unroll
    for (int i = 0; i < 4; ++i)
#pragma unroll
        for (int j = 0; j < 4; ++j)
            acc[i][j] = (v4f){0.f, 0.f, 0.f, 0.f};

#pragma unroll
    for (int kb = 0; kb < 4; ++kb) {
        const int cc = kb * 4 + kgrp;
        short8 af[4], bfr[4];
#pragma unroll
        for (int tm = 0; tm < 4; ++tm) {
            int rA = wm * 64 + tm * 16 + ml;
            af[tm] = *reinterpret_cast<const short8*>(&lA[(rA * 16 + (cc ^ (rA & 15))) * 8]);
        }
#pragma unroll
        for (int tn = 0; tn < 4; ++tn) {
            int rB = wn * 64 + tn * 16 + ml;
            bfr[tn] = *reinterpret_cast<const short8*>(&lB[(rB * 16 + (cc ^ (rB & 15))) * 8]);
        }
#pragma unroll
        for (int tm = 0; tm < 4; ++tm)
#pragma unroll
            for (int tn = 0; tn < 4; ++tn)
                acc[tm][tn] = __builtin_amdgcn_mfma_f32_16x16x32_bf16(af[tm], bfr[tn], acc[tm][tn], 0, 0, 0);
    }

    // C/D layout: col=lane&15, row=(lane>>4)*4+reg  [verified m89/m91]
    const int ncols = RC * 128;
    const int row0 = mb * 128 + wm * 64;
    const int col0 = rl * 128 + wn * 64;
#pragma unroll
    for (int tm = 0; tm < 4; ++tm)
#pragma unroll
        for (int rr = 0; rr < 4; ++rr) {
            int row = row0 + tm * 16 + kgrp * 4 + rr;
            size_t rb = (size_t)row * ncols;
#pragma unroll
            for (int tn = 0; tn < 4; ++tn) {
                int col = col0 + tn * 16 + ml;
                h2[rb + col] = f2bf_rne(acc[tm][tn][rr]);
            }
        }
}

// ---------------------------------------------------------------------------
// Gather: one wave per (chunk, node) segment; edges pre-sorted by (chunk,dst)
// so no filtering. Unroll x4 -> 4 independent 256 B h2 row loads in flight.
// ---------------------------------------------------------------------------
__global__ void gather(const int* __restrict__ off, const int* __restrict__ perm,
                       const unsigned short* __restrict__ h2,
                       const float* __restrict__ bias,
                       float* __restrict__ out, int c, int RC) {
    const int d = blockIdx.x * 4 + (threadIdx.x >> 6);
    const int lane = threadIdx.x & 63;
    const int kb = c * N_NODES + d;
    int e0 = off[kb], e1 = off[kb + 1];
    const size_t rowstride = (size_t)RC * 128;
    float2 acc = make_float2(0.f, 0.f);
    int e = e0;
    for (; e + 4 <= e1; e += 4) {
        int p0 = perm[e], p1 = perm[e + 1], p2 = perm[e + 2], p3 = perm[e + 3];
        const ushort2 v0 = *reinterpret_cast<const ushort2*>(h2 + (size_t)(p0 >> 4) * rowstride + (p0 & 15) * 128 + lane * 2);
        const ushort2 v1 = *reinterpret_cast<const ushort2*>(h2 + (size_t)(p1 >> 4) * rowstride + (p1 & 15) * 128 + lane * 2);
        const ushort2 v2 = *reinterpret_cast<const ushort2*>(h2 + (size_t)(p2 >> 4) * rowstride + (p2 & 15) * 128 + lane * 2);
        const ushort2 v3 = *reinterpret_cast<const ushort2*>(h2 + (size_t)(p3 >> 4) * rowstride + (p3 & 15) * 128 + lane * 2);
        acc.x += bf2f(v0.x) + bf2f(v1.x) + bf2f(v2.x) + bf2f(v3.x);
        acc.y += bf2f(v0.y) + bf2f(v1.y) + bf2f(v2.y) + bf2f(v3.y);
    }
    for (; e < e1; ++e) {
        int p = perm[e];
        const ushort2 v = *reinterpret_cast<const ushort2*>(h2 + (size_t)(p >> 4) * rowstride + (p & 15) * 128 + lane * 2);
        acc.x += bf2f(v.x);
        acc.y += bf2f(v.y);
    }
    float* po = out + (size_t)d * OUT_FEAT + lane * 2;
    if (c == 0) {
        acc.x += bias[lane * 2];
        acc.y += bias[lane * 2 + 1];
    } else {
        float2 prev = *reinterpret_cast<const float2*>(po);
        acc.x += prev.x;
        acc.y += prev.y;
    }
    *reinterpret_cast<float2*>(po) = acc;
}

static inline size_t align256(size_t a) { return (a + 255) & ~(size_t)255; }

extern "C" void kernel_launch(void* const* d_in, const int* in_sizes, int n_in,
                              void* d_out, int out_size, void* d_ws, size_t ws_size,
                              hipStream_t stream) {
    const float* x      = (const float*)d_in[0];
    const float* weight = (const float*)d_in[1];
    const float* w_comp = (const float*)d_in[2];
    const float* h_bias = (const float*)d_in[3];
    const int*   src    = (const int*)d_in[4];
    const int*   dst    = (const int*)d_in[5];
    const int*   etypes = (const int*)d_in[6];
    float* out = (float*)d_out;

    const size_t per_rel = (size_t)M_PAD * 128 * 2;   // 25,624,576 B

    // choose RC (relations per chunk) and lay out workspace
    int RC = 16, lg = 4;
    size_t off_o = 0, cnt_o = 0, h2_o = 0;
    for (;;) {
        int nch = NUM_RELS / RC;
        size_t K = (size_t)nch * N_NODES;
        size_t a = 0;
        a += 512 * 1024;                 // Bt
        size_t xb_o = a; a = align256(a + per_rel);          // xb (M_PAD rows bf16)
        size_t pm_o = a; a = align256(a + (size_t)N_EDGES * 4);   // perm
        size_t pt_o = a; a = align256(a + 4096);             // partials
        off_o = a; a = align256(a + (K + 1) * 4);            // off
        cnt_o = a; a = align256(a + K * 4);                  // count/cursor
        h2_o  = a; a += per_rel * RC;                        // h2
        (void)xb_o; (void)pm_o; (void)pt_o;
        if (a <= ws_size || RC == 1) break;
        RC >>= 1; lg -= 1;
    }
    const int nch = NUM_RELS / RC;
    const int K = nch * N_NODES;

    char* w = (char*)d_ws;
    unsigned short* Bt      = (unsigned short*)(w);
    unsigned short* xb      = (unsigned short*)(w + 512 * 1024);
    int*            perm    = (int*)(w + align256(512 * 1024 + per_rel));
    int*            partial = (int*)((char*)perm + align256((size_t)N_EDGES * 4));
    int*            off     = (int*)(w + off_o);
    int*            cnt     = (int*)(w + cnt_o);     // doubles as cursor
    unsigned short* h2      = (unsigned short*)(w + h2_o);

    const int G = (K + 4095) / 4096;   // scan blocks, <= 391

    conv_x<<<12512, 256, 0, stream>>>(x, xb);
    build_w<<<1024, 256, 0, stream>>>(weight, w_comp, Bt);

    zero_counts<<<(K + 255) / 256, 256, 0, stream>>>(cnt, K);
    hist<<<12500, 256, 0, stream>>>(dst, etypes, cnt, lg);
    scan_part<<<G, 256, 0, stream>>>(cnt, partial, K);
    scan_mid<<<1, 512, 0, stream>>>(partial, G, off, K);
    scan_final<<<G, 256, 0, stream>>>(cnt, partial, off, cnt, K);
    place<<<12500, 256, 0, stream>>>(src, dst, etypes, cnt, perm, lg, RC - 1);

    for (int c = 0; c < nch; ++c) {
        gemm_h<<<dim3(782, RC), 256, 0, stream>>>(xb, Bt, h2, c, RC);
        gather<<<25000, 256, 0, stream>>>(off, perm, h2, h_bias, out, c, RC);
    }
}

// Round 5
// 575.898 us; speedup vs baseline: 10.0823x; 1.4777x over previous
//
#include <hip/hip_runtime.h>
#include <hip/hip_bf16.h>
#include <stdint.h>

#define N_NODES   100000
#define N_EDGES   3200000
#define IN_FEAT   128
#define OUT_FEAT  128
#define NUM_RELS  16
#define NUM_BASES 8
#define M_PAD     100096      // 782 * 128
#define NBKT      391         // coarse buckets per chunk = ceil(100000/256)
#define NB        256         // blocks in coarse hist/place (must match both)

using short8 = __attribute__((ext_vector_type(8))) short;
using v4f    = __attribute__((ext_vector_type(4))) float;

__device__ inline unsigned short f2bf_rne(float f) {
    __hip_bfloat16 h = __float2bfloat16(f);
    return *reinterpret_cast<unsigned short*>(&h);
}
__device__ inline float bf2f(unsigned short u) {
    union { uint32_t i; float f; } x;
    x.i = ((uint32_t)u) << 16;
    return x.f;
}

// ---------------------------------------------------------------------------
// x fp32 -> bf16, zero-padded to M_PAD rows
// ---------------------------------------------------------------------------
__global__ void conv_x(const float* __restrict__ x, unsigned short* __restrict__ xb) {
    int id = blockIdx.x * 256 + threadIdx.x;
    int base = id * 4;
    ushort4 o;
    if (base < N_NODES * IN_FEAT) {
        const float4 v = reinterpret_cast<const float4*>(x)[id];
        o.x = f2bf_rne(v.x); o.y = f2bf_rne(v.y);
        o.z = f2bf_rne(v.z); o.w = f2bf_rne(v.w);
    } else {
        o.x = o.y = o.z = o.w = 0;
    }
    reinterpret_cast<ushort4*>(xb)[id] = o;
}

// ---------------------------------------------------------------------------
// Bt[n][k] = sum_b w_comp[r][b] * weight[b][k][o], n = r*128+o (bf16)
// ---------------------------------------------------------------------------
__global__ void build_w(const float* __restrict__ weight,
                        const float* __restrict__ w_comp,
                        unsigned short* __restrict__ Bt) {
    int id = blockIdx.x * 256 + threadIdx.x;
    int n = id >> 7;
    int k = id & 127;
    int r = n >> 7;
    int o = n & 127;
    float acc = 0.f;
#pragma unroll
    for (int b = 0; b < NUM_BASES; ++b)
        acc += w_comp[r * NUM_BASES + b] * weight[(b * IN_FEAT + k) * OUT_FEAT + o];
    Bt[id] = f2bf_rne(acc);
}

// ---------------------------------------------------------------------------
// Two-level sort by (chunk, dst). Coarse bucket b = chunk*NBKT + (dst>>8).
// Phase 1: per-block LDS histogram -> histG[b*NB + nb]  (no global atomics)
// ---------------------------------------------------------------------------
__global__ __launch_bounds__(1024) void coarse_hist(const int* __restrict__ dst,
                                                    const int* __restrict__ et,
                                                    int* __restrict__ histG,
                                                    int lg, int nbuck) {
    extern __shared__ int lh[];
    for (int i = threadIdx.x; i < nbuck; i += 1024) lh[i] = 0;
    __syncthreads();
    const int stride = NB * 1024;
    for (int e = blockIdx.x * 1024 + threadIdx.x; e < N_EDGES; e += stride)
        atomicAdd(&lh[(et[e] >> lg) * NBKT + (dst[e] >> 8)], 1);
    __syncthreads();
    for (int i = threadIdx.x; i < nbuck; i += 1024)
        histG[i * NB + blockIdx.x] = lh[i];
}

// ---------------------------------------------------------------------------
// 2-level in-place exclusive scan of data[0..K): part -> mid -> final
// ---------------------------------------------------------------------------
__global__ void scan_part(const int* __restrict__ data, int* __restrict__ partial, int K) {
    __shared__ int sh[256];
    const int tid = threadIdx.x, b = blockIdx.x;
    const int i0 = b * 4096 + tid * 16;
    int s = 0;
#pragma unroll
    for (int k = 0; k < 16; ++k) { int i = i0 + k; if (i < K) s += data[i]; }
    sh[tid] = s;
    __syncthreads();
    for (int st = 128; st > 0; st >>= 1) {
        if (tid < st) sh[tid] += sh[tid + st];
        __syncthreads();
    }
    if (tid == 0) partial[b] = sh[0];
}

__global__ __launch_bounds__(512) void scan_mid(int* __restrict__ partial, int G) {
    __shared__ int sh[512];
    const int tid = threadIdx.x;
    int v = (tid < G) ? partial[tid] : 0;
    sh[tid] = v;
    __syncthreads();
    for (int st = 1; st < 512; st <<= 1) {
        int t = (tid >= st) ? sh[tid - st] : 0;
        __syncthreads();
        sh[tid] += t;
        __syncthreads();
    }
    if (tid < G) partial[tid] = sh[tid] - v;        // exclusive
}

// in-place: each element read before overwrite by the same thread
__global__ void scan_final(int* __restrict__ data, const int* __restrict__ partial, int K) {
    __shared__ int sh[256];
    const int tid = threadIdx.x, b = blockIdx.x;
    const int i0 = b * 4096 + tid * 16;
    int s = 0;
#pragma unroll
    for (int k = 0; k < 16; ++k) { int i = i0 + k; if (i < K) s += data[i]; }
    sh[tid] = s;
    __syncthreads();
    for (int st = 1; st < 256; st <<= 1) {
        int t = (tid >= st) ? sh[tid - st] : 0;
        __syncthreads();
        sh[tid] += t;
        __syncthreads();
    }
    int run = partial[b] + sh[tid] - s;
#pragma unroll
    for (int k = 0; k < 16; ++k) {
        int i = i0 + k;
        if (i < K) {
            int c = data[i];
            data[i] = run;
            run += c;
        }
    }
}

// ---------------------------------------------------------------------------
// Phase 2: place edges into bucket-contiguous regions using exact reserved
// ranges (histS = scanned histG). LDS cursors only; writes are ~16-entry runs.
// entry = (dst&255)<<21 | src<<4 | rl   (29 bits)
// ---------------------------------------------------------------------------
__global__ __launch_bounds__(1024) void coarse_place(const int* __restrict__ src,
                                                     const int* __restrict__ dst,
                                                     const int* __restrict__ et,
                                                     const int* __restrict__ histS,
                                                     int* __restrict__ entries,
                                                     int lg, int RCm1, int nbuck) {
    extern __shared__ int cur[];
    for (int i = threadIdx.x; i < nbuck; i += 1024)
        cur[i] = histS[i * NB + blockIdx.x];
    __syncthreads();
    const int stride = NB * 1024;
    for (int e = blockIdx.x * 1024 + threadIdx.x; e < N_EDGES; e += stride) {
        int t = et[e], d = dst[e];
        int b = (t >> lg) * NBKT + (d >> 8);
        int pos = atomicAdd(&cur[b], 1);
        entries[pos] = ((d & 255) << 21) | (src[e] << 4) | (t & RCm1);
    }
}

// ---------------------------------------------------------------------------
// Phase 3: one block per bucket; counting sort by dst-low-8 in LDS (2-pass,
// no capacity limit). Emits coalesced perm runs AND per-node off[] directly.
// ---------------------------------------------------------------------------
__global__ __launch_bounds__(256) void fine_sort(const int* __restrict__ entries,
                                                 const int* __restrict__ histS,
                                                 int* __restrict__ perm,
                                                 int* __restrict__ off,
                                                 int nbuck, int nch) {
    __shared__ int cnt[256];
    __shared__ int bs[256];
    const int tid = threadIdx.x, b = blockIdx.x;
    const int start = histS[b * NB];
    const int end   = (b + 1 < nbuck) ? histS[(b + 1) * NB] : N_EDGES;

    cnt[tid] = 0;
    __syncthreads();
    for (int i = start + tid; i < end; i += 256)
        atomicAdd(&cnt[entries[i] >> 21], 1);
    __syncthreads();

    int v = cnt[tid];
    bs[tid] = v;
    __syncthreads();
    for (int st = 1; st < 256; st <<= 1) {
        int t = (tid >= st) ? bs[tid - st] : 0;
        __syncthreads();
        bs[tid] += t;
        __syncthreads();
    }
    const int excl = bs[tid] - v;      // exclusive prefix among dlow

    const int c  = b / NBKT;
    const int dh = b % NBKT;
    const int d  = dh * 256 + tid;
    if (d < N_NODES) off[c * N_NODES + d] = start + excl;
    if (b == nbuck - 1 && tid == 0) off[nch * N_NODES] = N_EDGES;

    __syncthreads();
    cnt[tid] = excl;                   // cursor
    __syncthreads();
    for (int i = start + tid; i < end; i += 256) {
        int en = entries[i];
        int p = atomicAdd(&cnt[en >> 21], 1);
        perm[start + p] = en & 0x1FFFFF;   // (src<<4)|rl
    }
}

// ---------------------------------------------------------------------------
// GEMM, m97-style: 128x128 tile, K=128 via global_load_lds(16B), XOR-swizzled
// ---------------------------------------------------------------------------
__global__ __launch_bounds__(256, 2) void gemm_h(const unsigned short* __restrict__ xb,
                                                 const unsigned short* __restrict__ Bt,
                                                 unsigned short* __restrict__ h2,
                                                 int c, int RC) {
    __shared__ unsigned short lA[128 * 128];
    __shared__ unsigned short lB[128 * 128];

    const int mb = blockIdx.x;
    const int rl = blockIdx.y;
    const int r  = c * RC + rl;
    const int tid  = threadIdx.x;
    const int wid  = tid >> 6;
    const int lane = tid & 63;

    const unsigned short* gA = xb + (size_t)mb * 128 * IN_FEAT;
    const unsigned short* gB = Bt + (size_t)r  * 128 * IN_FEAT;

#pragma unroll
    for (int it = 0; it < 8; ++it) {
        int sbase = it * 256 + wid * 64;
        int s = sbase + lane;
        int row = s >> 4;
        int cc = (s & 15) ^ (row & 15);
        __builtin_amdgcn_global_load_lds(
            (const __attribute__((address_space(1))) void*)(gA + row * 128 + cc * 8),
            (__attribute__((address_space(3))) void*)(&lA[sbase * 8]), 16, 0, 0);
    }
#pragma unroll
    for (int it = 0; it < 8; ++it) {
        int sbase = it * 256 + wid * 64;
        int s = sbase + lane;
        int row = s >> 4;
        int cc = (s & 15) ^ (row & 15);
        __builtin_amdgcn_global_load_lds(
            (const __attribute__((address_space(1))) void*)(gB + row * 128 + cc * 8),
            (__attribute__((address_space(3))) void*)(&lB[sbase * 8]), 16, 0, 0);
    }
    __syncthreads();

    const int wm = wid >> 1, wn = wid & 1;
    const int ml = lane & 15, kgrp = lane >> 4;

    v4f acc[4][4];
#pragma unroll
    for (int i = 0; i < 4; ++i)
#pragma unroll
        for (int j = 0; j < 4; ++j)
            acc[i][j] = (v4f){0.f, 0.f, 0.f, 0.f};

#pragma unroll
    for (int kb = 0; kb < 4; ++kb) {
        const int cc = kb * 4 + kgrp;
        short8 af[4], bfr[4];
#pragma unroll
        for (int tm = 0; tm < 4; ++tm) {
            int rA = wm * 64 + tm * 16 + ml;
            af[tm] = *reinterpret_cast<const short8*>(&lA[(rA * 16 + (cc ^ (rA & 15))) * 8]);
        }
#pragma unroll
        for (int tn = 0; tn < 4; ++tn) {
            int rB = wn * 64 + tn * 16 + ml;
            bfr[tn] = *reinterpret_cast<const short8*>(&lB[(rB * 16 + (cc ^ (rB & 15))) * 8]);
        }
#pragma unroll
        for (int tm = 0; tm < 4; ++tm)
#pragma unroll
            for (int tn = 0; tn < 4; ++tn)
                acc[tm][tn] = __builtin_amdgcn_mfma_f32_16x16x32_bf16(af[tm], bfr[tn], acc[tm][tn], 0, 0, 0);
    }

    const int ncols = RC * 128;
    const int row0 = mb * 128 + wm * 64;
    const int col0 = rl * 128 + wn * 64;
#pragma unroll
    for (int tm = 0; tm < 4; ++tm)
#pragma unroll
        for (int rr = 0; rr < 4; ++rr) {
            int row = row0 + tm * 16 + kgrp * 4 + rr;
            size_t rb = (size_t)row * ncols;
#pragma unroll
            for (int tn = 0; tn < 4; ++tn) {
                int col = col0 + tn * 16 + ml;
                h2[rb + col] = f2bf_rne(acc[tm][tn][rr]);
            }
        }
}

// ---------------------------------------------------------------------------
// Gather: one wave per (chunk, node) segment; unroll x4 for MLP.
// ---------------------------------------------------------------------------
__global__ void gather(const int* __restrict__ off, const int* __restrict__ perm,
                       const unsigned short* __restrict__ h2,
                       const float* __restrict__ bias,
                       float* __restrict__ out, int c, int RC) {
    const int d = blockIdx.x * 4 + (threadIdx.x >> 6);
    const int lane = threadIdx.x & 63;
    const int kb = c * N_NODES + d;
    int e0 = off[kb], e1 = off[kb + 1];
    const size_t rowstride = (size_t)RC * 128;
    float2 acc = make_float2(0.f, 0.f);
    int e = e0;
    for (; e + 4 <= e1; e += 4) {
        int p0 = perm[e], p1 = perm[e + 1], p2 = perm[e + 2], p3 = perm[e + 3];
        const ushort2 v0 = *reinterpret_cast<const ushort2*>(h2 + (size_t)(p0 >> 4) * rowstride + (p0 & 15) * 128 + lane * 2);
        const ushort2 v1 = *reinterpret_cast<const ushort2*>(h2 + (size_t)(p1 >> 4) * rowstride + (p1 & 15) * 128 + lane * 2);
        const ushort2 v2 = *reinterpret_cast<const ushort2*>(h2 + (size_t)(p2 >> 4) * rowstride + (p2 & 15) * 128 + lane * 2);
        const ushort2 v3 = *reinterpret_cast<const ushort2*>(h2 + (size_t)(p3 >> 4) * rowstride + (p3 & 15) * 128 + lane * 2);
        acc.x += bf2f(v0.x) + bf2f(v1.x) + bf2f(v2.x) + bf2f(v3.x);
        acc.y += bf2f(v0.y) + bf2f(v1.y) + bf2f(v2.y) + bf2f(v3.y);
    }
    for (; e < e1; ++e) {
        int p = perm[e];
        const ushort2 v = *reinterpret_cast<const ushort2*>(h2 + (size_t)(p >> 4) * rowstride + (p & 15) * 128 + lane * 2);
        acc.x += bf2f(v.x);
        acc.y += bf2f(v.y);
    }
    float* po = out + (size_t)d * OUT_FEAT + lane * 2;
    if (c == 0) {
        acc.x += bias[lane * 2];
        acc.y += bias[lane * 2 + 1];
    } else {
        float2 prev = *reinterpret_cast<const float2*>(po);
        acc.x += prev.x;
        acc.y += prev.y;
    }
    *reinterpret_cast<float2*>(po) = acc;
}

static inline size_t align256(size_t a) { return (a + 255) & ~(size_t)255; }

extern "C" void kernel_launch(void* const* d_in, const int* in_sizes, int n_in,
                              void* d_out, int out_size, void* d_ws, size_t ws_size,
                              hipStream_t stream) {
    const float* x      = (const float*)d_in[0];
    const float* weight = (const float*)d_in[1];
    const float* w_comp = (const float*)d_in[2];
    const float* h_bias = (const float*)d_in[3];
    const int*   src    = (const int*)d_in[4];
    const int*   dst    = (const int*)d_in[5];
    const int*   etypes = (const int*)d_in[6];
    float* out = (float*)d_out;

    const size_t per_rel = (size_t)M_PAD * 128 * 2;   // 25,624,576 B

    // Choose RC and lay out workspace. entries/histG alias h2 (dead before gemm).
    int RC = 16, lg = 4;
    size_t perm_o = 0, off_o = 0, part_o = 0, h2_o = 0;
    for (;;) {
        int nch = NUM_RELS / RC;
        size_t a = 512 * 1024;                                   // Bt
        a = align256(a + per_rel);                               // xb
        perm_o = a; a = align256(a + (size_t)N_EDGES * 4);       // perm
        off_o  = a; a = align256(a + ((size_t)nch * N_NODES + 1) * 4);
        part_o = a; a = align256(a + 512 * 4);                   // scan partials
        h2_o   = a; a += per_rel * (size_t)RC;                   // h2 (>= 25.6MB)
        if (a <= ws_size || RC == 1) break;
        RC >>= 1; lg -= 1;
    }
    const int nch = NUM_RELS / RC;
    const int nbuck = nch * NBKT;
    const int K2 = nbuck * NB;
    const int G2 = (K2 + 4095) / 4096;

    char* w = (char*)d_ws;
    unsigned short* Bt      = (unsigned short*)(w);
    unsigned short* xb      = (unsigned short*)(w + 512 * 1024);
    int*            perm    = (int*)(w + perm_o);
    int*            off     = (int*)(w + off_o);
    int*            partial = (int*)(w + part_o);
    unsigned short* h2      = (unsigned short*)(w + h2_o);
    int*            entries = (int*)(w + h2_o);                  // alias h2[0..12.8MB)
    int*            histG   = (int*)(w + h2_o + 13 * 1024 * 1024); // alias h2[13MB..)

    conv_x<<<12512, 256, 0, stream>>>(x, xb);
    build_w<<<1024, 256, 0, stream>>>(weight, w_comp, Bt);

    coarse_hist<<<NB, 1024, nbuck * 4, stream>>>(dst, etypes, histG, lg, nbuck);
    scan_part<<<G2, 256, 0, stream>>>(histG, partial, K2);
    scan_mid<<<1, 512, 0, stream>>>(partial, G2);
    scan_final<<<G2, 256, 0, stream>>>(histG, partial, K2);
    coarse_place<<<NB, 1024, nbuck * 4, stream>>>(src, dst, etypes, histG, entries,
                                                  lg, RC - 1, nbuck);
    fine_sort<<<nbuck, 256, 0, stream>>>(entries, histG, perm, off, nbuck, nch);

    for (int c = 0; c < nch; ++c) {
        gemm_h<<<dim3(782, RC), 256, 0, stream>>>(xb, Bt, h2, c, RC);
        gather<<<25000, 256, 0, stream>>>(off, perm, h2, h_bias, out, c, RC);
    }
}